// Round 8
// baseline (212.123 us; speedup 1.0000x reference)
//
#include <hip/hip_runtime.h>

typedef unsigned short ushort_t;
typedef unsigned int   uint32;
typedef unsigned long long u64;
typedef __bf16 bf16_t;
typedef bf16_t bf16x8 __attribute__((ext_vector_type(8)));
typedef float  f32x4  __attribute__((ext_vector_type(4)));

#define N_TOK 4096
#define C_DIM 128
#define NTOT  8192
#define THRESH2 64.0f
#define AGG_BLOCKS 1024

// workspace layout (bytes)
#define XF_OFF  (0u)                      // bf16 [8192][128]  token-major xf (bf16)
#define YF_OFF  (2u<<20)                  // f32  [8192][128]  y
#define SQ_OFF  (14u<<20)                 // f32  [8192]
#define BN_OFF  ((14u<<20) + 32768u)      // f32  [8][256] partitioned bn partials
#define CNT_OFF (BN_OFF + 8192u)          // uint arrival counter
#define HB_OFF  (16u<<20)                 // u64  [8192][64] bitmask rows
#define WS_NEED ((size_t)(24u<<20))

__device__ __forceinline__ ushort_t f2b(float f){
    uint32 u = __float_as_uint(f);
    u += 0x7fffu + ((u>>16)&1u);
    return (ushort_t)(u>>16);
}
__device__ __forceinline__ u64 shfl_u64(u64 v, int src){
    uint32 lo = (uint32)v, hi = (uint32)(v>>32);
    lo = __shfl(lo, src); hi = __shfl(hi, src);
    return ((u64)hi<<32)|lo;
}
__device__ __forceinline__ u64 shfl_xor_u64(u64 v, int m){
    uint32 lo = (uint32)v, hi = (uint32)(v>>32);
    lo = __shfl_xor(lo, m); hi = __shfl_xor(hi, m);
    return ((u64)hi<<32)|lo;
}
__device__ __forceinline__ int wave_popc_reduce(u64 w){
    int cnt = __builtin_popcountll(w);
    cnt += __shfl_xor(cnt, 1);
    cnt += __shfl_xor(cnt, 2);
    cnt += __shfl_xor(cnt, 4);
    cnt += __shfl_xor(cnt, 8);
    cnt += __shfl_xor(cnt, 16);
    cnt += __shfl_xor(cnt, 32);
    return cnt;
}

// K1: fused transpose + FC (MFMA) + sq + Xf(bf16) write. (proven)
// Block (0,0) additionally zeroes bn partials and the arrival counter.
__global__ __launch_bounds__(256) void k_fc(const float* __restrict__ x,
                                            const float* __restrict__ W,
                                            const float* __restrict__ bfc,
                                            ushort_t* __restrict__ Xf,
                                            float* __restrict__ Yf,
                                            float* __restrict__ sq,
                                            float* __restrict__ bnp,
                                            uint32* __restrict__ cnt){
    __shared__ ushort_t Xs[64*136];    // 64 tokens x 128 c (stride 136)
    __shared__ ushort_t Ws[64*136];    // 64 d x 128 c
    int tid = threadIdx.x;
    int t0 = blockIdx.x * 64;          // flat token base (0..8191)
    int dh = blockIdx.y;               // d-half
    int b  = t0 >> 12;
    int n0 = t0 & 4095;
    if (blockIdx.x == 0 && dh == 0){
        #pragma unroll
        for (int k=0;k<8;k++) bnp[tid + 256*k] = 0.f;
        if (tid == 0) *cnt = 0u;
    }
    const float* xb = x + (size_t)b * C_DIM * N_TOK + n0;
    #pragma unroll
    for (int k=0;k<8;k++){
        int idx = tid + 256*k;         // 2048 float4s = 64 n x 128 c
        int c = idx >> 4, n4 = (idx & 15)*4;
        float4 v = *(const float4*)(xb + (size_t)c*N_TOK + n4);
        Xs[(n4+0)*136 + c] = f2b(v.x);
        Xs[(n4+1)*136 + c] = f2b(v.y);
        Xs[(n4+2)*136 + c] = f2b(v.z);
        Xs[(n4+3)*136 + c] = f2b(v.w);
    }
    const float* Wb = W + (size_t)dh*64*C_DIM;
    #pragma unroll
    for (int k=0;k<8;k++){
        int idx = tid + 256*k;         // 2048 float4s = 64 d x 128 c
        int d = idx >> 5, c4 = (idx & 31)*4;
        float4 v = *(const float4*)(Wb + d*C_DIM + c4);
        uint2 u;
        u.x = (uint32)f2b(v.x) | ((uint32)f2b(v.y)<<16);
        u.y = (uint32)f2b(v.z) | ((uint32)f2b(v.w)<<16);
        *(uint2*)(&Ws[d*136 + c4]) = u;
    }
    __syncthreads();
    // write Xf rows [dh*32, dh*32+32) (coalesced 16B)
    #pragma unroll
    for (int k=0;k<2;k++){
        int idx = tid + 256*(k + 2*dh);
        int row = idx >> 4, c8 = (idx & 15)*8;
        uint4 o = *(const uint4*)(&Xs[row*136 + c8]);
        *(uint4*)(Xf + (size_t)(t0 + row)*C_DIM + c8) = o;
    }
    // sq[token] = sum_c xf^2 (dh==0 only)
    if (dh == 0){
        int tok = tid >> 2, p = tid & 3;
        const ushort_t* xr = &Xs[tok*136 + p*32];
        float sacc = 0.f;
        #pragma unroll
        for (int i=0;i<16;i++){
            uint32 u = *(const uint32*)(&xr[i*2]);
            float v0 = __uint_as_float(u<<16);
            float v1 = __uint_as_float(u & 0xffff0000u);
            sacc = fmaf(v0, v0, sacc);
            sacc = fmaf(v1, v1, sacc);
        }
        sacc += __shfl_xor(sacc, 1);
        sacc += __shfl_xor(sacc, 2);
        if (p == 0) sq[t0 + tok] = sacc;
    }
    // MFMA: y[tok][dh*64 + d] = sum_c Xs[tok][c] * Ws[d][c]
    int wv = tid >> 6, lane = tid & 63;
    int qd = lane >> 4, m = lane & 15;
    f32x4 acc[4] = {{0,0,0,0},{0,0,0,0},{0,0,0,0},{0,0,0,0}};
    #pragma unroll
    for (int kc=0;kc<4;kc++){
        bf16x8 af = *(const bf16x8*)(&Xs[(wv*16 + m)*136 + kc*32 + qd*8]);
        #pragma unroll
        for (int ct=0;ct<4;ct++){
            bf16x8 bfr = *(const bf16x8*)(&Ws[(ct*16+m)*136 + kc*32 + qd*8]);
            acc[ct] = __builtin_amdgcn_mfma_f32_16x16x32_bf16(af, bfr, acc[ct], 0, 0, 0);
        }
    }
    int row = t0 + wv*16 + qd*4;
    #pragma unroll
    for (int ct=0;ct<4;ct++){
        int d = dh*64 + ct*16 + m;
        float bias = bfc[d];
        #pragma unroll
        for (int r=0;r<4;r++)
            Yf[(size_t)(row + r)*C_DIM + d] = acc[ct][r] + bias;
    }
}

// K2: symmetric Gram, 128x64 tiles, XOR-swizzled LDS. (proven R7)
__global__ __launch_bounds__(256) void k_gram(const ushort_t* __restrict__ Xf,
                                              const float* __restrict__ sq,
                                              u64* __restrict__ Hb){
    __shared__ ushort_t Al[128*128];   // 32 KB, swizzled
    __shared__ ushort_t Bl[64*128];    // 16 KB, swizzled
    __shared__ u64 rowW[128];
    __shared__ u64 part[256];
    int tid = threadIdx.x;
    int L = blockIdx.x, b = blockIdx.y;
    int bi = (int)((65.0f - sqrtf(4225.0f - 4.0f*(float)L)) * 0.5f);
    while (bi > 0 && bi*(65-bi) > L) --bi;
    while ((bi+1)*(65-(bi+1)) <= L) ++bi;
    int bj = L - bi*(65-bi) + 2*bi;
    int i0 = bi*128, j0 = bj*64;
    const ushort_t* XfA = Xf + (size_t)(b*N_TOK + i0)*C_DIM;
    const ushort_t* XfB = Xf + (size_t)(b*N_TOK + j0)*C_DIM;
    #pragma unroll
    for (int k=0;k<8;k++){
        int q = tid + 256*k;            // 2048 x 16B : 128 rows
        int row = q >> 4, c16 = q & 15;
        int off = row*256 + ((c16*16) ^ ((row & 7) << 4));
        *(uint4*)((char*)Al + off) = *(const uint4*)(XfA + row*C_DIM + c16*8);
    }
    #pragma unroll
    for (int k=0;k<4;k++){
        int q = tid + 256*k;            // 1024 x 16B : 64 rows
        int row = q >> 4, c16 = q & 15;
        int off = row*256 + ((c16*16) ^ ((row & 7) << 4));
        *(uint4*)((char*)Bl + off) = *(const uint4*)(XfB + row*C_DIM + c16*8);
    }
    __syncthreads();
    int wv = tid >> 6, lane = tid & 63;
    int qd = lane >> 4, m = lane & 15;
    f32x4 acc[2][4] = {{{0,0,0,0},{0,0,0,0},{0,0,0,0},{0,0,0,0}},
                       {{0,0,0,0},{0,0,0,0},{0,0,0,0},{0,0,0,0}}};
    #pragma unroll
    for (int kc=0;kc<4;kc++){
        int coff = (kc*64 + qd*16) ^ ((m & 7) << 4);
        bf16x8 a0 = *(const bf16x8*)((char*)Al + (wv*32 +      m)*256 + coff);
        bf16x8 a1 = *(const bf16x8*)((char*)Al + (wv*32 + 16 + m)*256 + coff);
        #pragma unroll
        for (int ct=0;ct<4;ct++){
            bf16x8 bfr = *(const bf16x8*)((char*)Bl + (ct*16 + m)*256 + coff);
            acc[0][ct] = __builtin_amdgcn_mfma_f32_16x16x32_bf16(a0, bfr, acc[0][ct], 0, 0, 0);
            acc[1][ct] = __builtin_amdgcn_mfma_f32_16x16x32_bf16(a1, bfr, acc[1][ct], 0, 0, 0);
        }
    }
    float sqj[4];
    #pragma unroll
    for (int ct=0;ct<4;ct++) sqj[ct] = sq[b*N_TOK + j0 + ct*16 + m];
    #pragma unroll
    for (int rt=0;rt<2;rt++){
        int lr = wv*32 + rt*16 + qd*4;
        int ib = i0 + lr;
        float sqi[4];
        #pragma unroll
        for (int r=0;r<4;r++) sqi[r] = sq[b*N_TOK + ib + r];
        #pragma unroll
        for (int r=0;r<4;r++){
            u64 bits = 0;
            #pragma unroll
            for (int ct=0;ct<4;ct++){
                float d2 = sqi[r] + sqj[ct] - 2.0f*acc[rt][ct][r];
                if (d2 < THRESH2) bits |= (u64)1 << (ct*16 + m);
            }
            bits |= shfl_xor_u64(bits, 1);
            bits |= shfl_xor_u64(bits, 2);
            bits |= shfl_xor_u64(bits, 4);
            bits |= shfl_xor_u64(bits, 8);
            if (m == 0){
                Hb[(size_t)(b*N_TOK + ib + r)*64 + bj] = bits;
                rowW[lr + r] = bits;
            }
        }
    }
    __syncthreads();
    {
        int jj = tid & 63, hw = (tid>>6)&1, sub = tid>>7;
        u64 p = 0;
        int ibase = hw*64 + sub*32;
        #pragma unroll 8
        for (int ii=0; ii<32; ii++){
            u64 wrd = rowW[ibase + ii];
            p |= ((wrd >> jj) & 1ull) << (sub*32 + ii);
        }
        part[tid] = p;
    }
    __syncthreads();
    if (tid < 128){
        int jj = tid & 63, hw = tid >> 6;
        u64 wt = part[tid] | part[tid + 128];
        Hb[(size_t)(b*N_TOK + j0 + jj)*64 + 2*bi + hw] = wt;
    }
}

// K3: two-hop aggregation + BN stats + in-kernel grid barrier + BN/SiLU/out.
// Grid EXACTLY 1024 blocks @ __launch_bounds__(256,4): 4 blocks/CU x 256 CU
// = whole grid co-resident by capacity => arrive-then-spin is deadlock-free.
// Spin polls with atomicAdd(cnt,0) (RMW -> coherence point, no stale reads).
// Xe never touches global memory (lives in registers across the barrier).
__global__ __launch_bounds__(256, 4) void k_agg_out(const u64* __restrict__ Hb,
                                                    const float* __restrict__ Yf,
                                                    float* __restrict__ bnp,
                                                    uint32* __restrict__ cnt,
                                                    const float* __restrict__ gamma,
                                                    const float* __restrict__ beta,
                                                    float* __restrict__ out){
    __shared__ float r1[4][128];
    __shared__ float r2[4][128];
    __shared__ float tile[128*9];           // [c][n] padded, 4.5 KB
    int tid = threadIdx.x;
    int wv = tid >> 6, lane = tid & 63;
    int row0 = blockIdx.x * 8;              // 8 consecutive rows per block
    int b = row0 >> 12;
    const float* Vb = Yf + (size_t)b*N_TOK*C_DIM;
    float xe0a, xe1a, xe0b, xe1b;
    float s1a=0.f, s1b=0.f, s2a=0.f, s2b=0.f;
    #pragma unroll
    for (int k=0;k<2;k++){
        int row = row0 + wv + 4*k;
        u64 myw = Hb[(size_t)row*64 + lane];
        int ci = wave_popc_reduce(myw);
        float nrm_i = (ci > 0) ? 1.0f/(float)ci : 0.0f;
        float acc0 = 0.f, acc1 = 0.f;
        u64 nz = __ballot(myw != 0);
        while (nz){
            int wdi = __builtin_ctzll(nz);
            nz &= nz - 1;
            u64 mw = shfl_u64(myw, wdi);
            while (mw){
                int j = wdi*64 + __builtin_ctzll(mw);
                mw &= mw - 1;
                int jrow = (b << 12) + j;
                u64 jw; float nrm_j;
                if (jrow == row){ jw = myw; nrm_j = nrm_i; }
                else {
                    jw = Hb[(size_t)jrow*64 + lane];
                    int jc = wave_popc_reduce(jw);
                    nrm_j = (jc > 0) ? 1.0f/(float)jc : 0.0f;
                }
                float sub0 = 0.f, sub1 = 0.f;
                u64 jnz = __ballot(jw != 0);
                while (jnz){
                    int w2 = __builtin_ctzll(jnz);
                    jnz &= jnz - 1;
                    u64 m2 = shfl_u64(jw, w2);
                    while (m2){
                        int kk = w2*64 + __builtin_ctzll(m2);
                        m2 &= m2 - 1;
                        sub0 += Vb[(size_t)kk*C_DIM + lane];
                        sub1 += Vb[(size_t)kk*C_DIM + lane + 64];
                    }
                }
                acc0 += nrm_j * sub0;
                acc1 += nrm_j * sub1;
            }
        }
        size_t o = (size_t)row*C_DIM;
        float v0 = Yf[o + lane]      + nrm_i*acc0;
        float v1 = Yf[o + lane + 64] + nrm_i*acc1;
        if (k == 0){ xe0a = v0; xe1a = v1; } else { xe0b = v0; xe1b = v1; }
        s1a += v0; s2a += v0*v0;
        s1b += v1; s2b += v1*v1;
    }
    r1[wv][lane]      = s1a;
    r1[wv][lane + 64] = s1b;
    r2[wv][lane]      = s2a;
    r2[wv][lane + 64] = s2b;
    __syncthreads();
    if (tid < 128){
        float s1 = r1[0][tid]+r1[1][tid]+r1[2][tid]+r1[3][tid];
        float s2 = r2[0][tid]+r2[1][tid]+r2[2][tid]+r2[3][tid];
        int prt = blockIdx.x & 7;
        atomicAdd(&bnp[prt*256 + tid],       s1);
        atomicAdd(&bnp[prt*256 + 128 + tid], s2);
    }
    __threadfence();
    __syncthreads();
    // arrive, then spin until all 1024 blocks arrived
    if (tid == 0){
        __hip_atomic_fetch_add(cnt, 1u, __ATOMIC_RELEASE, __HIP_MEMORY_SCOPE_AGENT);
        while (__hip_atomic_fetch_add(cnt, 0u, __ATOMIC_ACQUIRE, __HIP_MEMORY_SCOPE_AGENT)
               < (uint32)AGG_BLOCKS)
            __builtin_amdgcn_s_sleep(2);
    }
    __syncthreads();
    // BN stats for this thread's two channels (coherent loads of bnp)
    float inv = 1.0f / (float)NTOT;
    float scl_l, sft_l, scl_h, sft_h;
    {
        int cl = lane, ch = lane + 64;
        float a1=0.f,a2=0.f,b1=0.f,b2=0.f;
        #pragma unroll
        for (int p=0;p<8;p++){
            a1 += __hip_atomic_load(&bnp[p*256 + cl],       __ATOMIC_RELAXED, __HIP_MEMORY_SCOPE_AGENT);
            a2 += __hip_atomic_load(&bnp[p*256 + 128 + cl], __ATOMIC_RELAXED, __HIP_MEMORY_SCOPE_AGENT);
            b1 += __hip_atomic_load(&bnp[p*256 + ch],       __ATOMIC_RELAXED, __HIP_MEMORY_SCOPE_AGENT);
            b2 += __hip_atomic_load(&bnp[p*256 + 128 + ch], __ATOMIC_RELAXED, __HIP_MEMORY_SCOPE_AGENT);
        }
        float mean = a1*inv, var = a2*inv - mean*mean;
        scl_l = gamma[cl] * rsqrtf(var + 1e-5f);
        sft_l = beta[cl] - mean*scl_l;
        mean = b1*inv; var = b2*inv - mean*mean;
        scl_h = gamma[ch] * rsqrtf(var + 1e-5f);
        sft_h = beta[ch] - mean*scl_h;
    }
    // apply BN + SiLU, stage to [c][n] padded tile
    #pragma unroll
    for (int k=0;k<2;k++){
        float v0 = (k==0) ? xe0a : xe0b;
        float v1 = (k==0) ? xe1a : xe1b;
        v0 = scl_l*v0 + sft_l;
        v1 = scl_h*v1 + sft_h;
        v0 = v0 / (1.0f + __expf(-v0));
        v1 = v1 / (1.0f + __expf(-v1));
        int n = wv + 4*k;
        tile[lane*9 + n]       = v0;
        tile[(lane+64)*9 + n]  = v1;
    }
    __syncthreads();
    // write out[b][c][n0..n0+7]: 2 float4 runs per c (32B contiguity)
    {
        int c = tid >> 1, n4 = (tid & 1)*4;
        float4 v;
        v.x = tile[c*9 + n4 + 0];
        v.y = tile[c*9 + n4 + 1];
        v.z = tile[c*9 + n4 + 2];
        v.w = tile[c*9 + n4 + 3];
        *(float4*)(out + (size_t)(b*C_DIM + c)*N_TOK + (row0 & 4095) + n4) = v;
    }
}

extern "C" void kernel_launch(void* const* d_in, const int* in_sizes, int n_in,
                              void* d_out, int out_size, void* d_ws, size_t ws_size,
                              hipStream_t stream){
    if (ws_size < WS_NEED) return;
    const float* x     = (const float*)d_in[0];
    const float* W     = (const float*)d_in[1];
    const float* bfc   = (const float*)d_in[2];
    const float* gamma = (const float*)d_in[3];
    const float* beta  = (const float*)d_in[4];
    char* ws = (char*)d_ws;
    ushort_t* Xf = (ushort_t*)(ws + XF_OFF);
    float*    Yf = (float*)(ws + YF_OFF);
    float*    sqp= (float*)(ws + SQ_OFF);
    float*    bnp= (float*)(ws + BN_OFF);
    uint32*   cnt= (uint32*)(ws + CNT_OFF);
    u64*      Hb = (u64*)(ws + HB_OFF);
    float*    outp = (float*)d_out;

    k_fc     <<<dim3(128,2),    dim3(256), 0, stream>>>(x, W, bfc, Xf, Yf, sqp, bnp, cnt);
    k_gram   <<<dim3(1056,2),   dim3(256), 0, stream>>>(Xf, sqp, Hb);
    k_agg_out<<<dim3(AGG_BLOCKS),dim3(256),0, stream>>>(Hb, Yf, bnp, cnt, gamma, beta, outp);
}

// Round 9
// 101.824 us; speedup vs baseline: 2.0832x; 2.0832x over previous
//
#include <hip/hip_runtime.h>

typedef unsigned short ushort_t;
typedef unsigned int   uint32;
typedef unsigned long long u64;
typedef __bf16 bf16_t;
typedef bf16_t bf16x8 __attribute__((ext_vector_type(8)));
typedef float  f32x4  __attribute__((ext_vector_type(4)));

#define N_TOK 4096
#define C_DIM 128
#define NTOT  8192
#define THRESH2 64.0f

// workspace layout (bytes)
#define XF_OFF  (0u)                      // bf16 [8192][128]  token-major xf (bf16)
#define YF_OFF  (2u<<20)                  // f32  [8192][128]  y
#define XE_OFF  (10u<<20)                 // f32  [8192][128]  xe
#define SQ_OFF  (14u<<20)                 // f32  [8192]
#define BN_OFF  ((14u<<20) + 32768u)      // f32  [8][256] partitioned bn partials
#define HB_OFF  (16u<<20)                 // u64  [8192][64] bitmask rows
#define WS_NEED ((size_t)(24u<<20))

__device__ __forceinline__ ushort_t f2b(float f){
    uint32 u = __float_as_uint(f);
    u += 0x7fffu + ((u>>16)&1u);
    return (ushort_t)(u>>16);
}
__device__ __forceinline__ u64 shfl_u64(u64 v, int src){
    uint32 lo = (uint32)v, hi = (uint32)(v>>32);
    lo = __shfl(lo, src); hi = __shfl(hi, src);
    return ((u64)hi<<32)|lo;
}
__device__ __forceinline__ u64 shfl_xor_u64(u64 v, int m){
    uint32 lo = (uint32)v, hi = (uint32)(v>>32);
    lo = __shfl_xor(lo, m); hi = __shfl_xor(hi, m);
    return ((u64)hi<<32)|lo;
}
__device__ __forceinline__ int wave_popc_reduce(u64 w){
    int cnt = __builtin_popcountll(w);
    cnt += __shfl_xor(cnt, 1);
    cnt += __shfl_xor(cnt, 2);
    cnt += __shfl_xor(cnt, 4);
    cnt += __shfl_xor(cnt, 8);
    cnt += __shfl_xor(cnt, 16);
    cnt += __shfl_xor(cnt, 32);
    return cnt;
}

// K1: fused transpose + FC (MFMA) + sq + Xf(bf16) write. (proven R5/R7)
__global__ __launch_bounds__(256) void k_fc(const float* __restrict__ x,
                                            const float* __restrict__ W,
                                            const float* __restrict__ bfc,
                                            ushort_t* __restrict__ Xf,
                                            float* __restrict__ Yf,
                                            float* __restrict__ sq,
                                            float* __restrict__ bnp){
    __shared__ ushort_t Xs[64*136];    // 64 tokens x 128 c (stride 136)
    __shared__ ushort_t Ws[64*136];    // 64 d x 128 c
    int tid = threadIdx.x;
    int t0 = blockIdx.x * 64;          // flat token base (0..8191)
    int dh = blockIdx.y;               // d-half
    int b  = t0 >> 12;
    int n0 = t0 & 4095;
    if (blockIdx.x == 0 && dh == 0){
        #pragma unroll
        for (int k=0;k<8;k++) bnp[tid + 256*k] = 0.f;
    }
    const float* xb = x + (size_t)b * C_DIM * N_TOK + n0;
    #pragma unroll
    for (int k=0;k<8;k++){
        int idx = tid + 256*k;         // 2048 float4s = 64 n x 128 c
        int c = idx >> 4, n4 = (idx & 15)*4;
        float4 v = *(const float4*)(xb + (size_t)c*N_TOK + n4);
        Xs[(n4+0)*136 + c] = f2b(v.x);
        Xs[(n4+1)*136 + c] = f2b(v.y);
        Xs[(n4+2)*136 + c] = f2b(v.z);
        Xs[(n4+3)*136 + c] = f2b(v.w);
    }
    const float* Wb = W + (size_t)dh*64*C_DIM;
    #pragma unroll
    for (int k=0;k<8;k++){
        int idx = tid + 256*k;         // 2048 float4s = 64 d x 128 c
        int d = idx >> 5, c4 = (idx & 31)*4;
        float4 v = *(const float4*)(Wb + d*C_DIM + c4);
        uint2 u;
        u.x = (uint32)f2b(v.x) | ((uint32)f2b(v.y)<<16);
        u.y = (uint32)f2b(v.z) | ((uint32)f2b(v.w)<<16);
        *(uint2*)(&Ws[d*136 + c4]) = u;
    }
    __syncthreads();
    // write Xf rows [dh*32, dh*32+32) (coalesced 16B)
    #pragma unroll
    for (int k=0;k<2;k++){
        int idx = tid + 256*(k + 2*dh);
        int row = idx >> 4, c8 = (idx & 15)*8;
        uint4 o = *(const uint4*)(&Xs[row*136 + c8]);
        *(uint4*)(Xf + (size_t)(t0 + row)*C_DIM + c8) = o;
    }
    // sq[token] = sum_c xf^2 (dh==0 only)
    if (dh == 0){
        int tok = tid >> 2, p = tid & 3;
        const ushort_t* xr = &Xs[tok*136 + p*32];
        float sacc = 0.f;
        #pragma unroll
        for (int i=0;i<16;i++){
            uint32 u = *(const uint32*)(&xr[i*2]);
            float v0 = __uint_as_float(u<<16);
            float v1 = __uint_as_float(u & 0xffff0000u);
            sacc = fmaf(v0, v0, sacc);
            sacc = fmaf(v1, v1, sacc);
        }
        sacc += __shfl_xor(sacc, 1);
        sacc += __shfl_xor(sacc, 2);
        if (p == 0) sq[t0 + tok] = sacc;
    }
    // MFMA: y[tok][dh*64 + d] = sum_c Xs[tok][c] * Ws[d][c]
    int wv = tid >> 6, lane = tid & 63;
    int qd = lane >> 4, m = lane & 15;
    f32x4 acc[4] = {{0,0,0,0},{0,0,0,0},{0,0,0,0},{0,0,0,0}};
    #pragma unroll
    for (int kc=0;kc<4;kc++){
        bf16x8 af = *(const bf16x8*)(&Xs[(wv*16 + m)*136 + kc*32 + qd*8]);
        #pragma unroll
        for (int ct=0;ct<4;ct++){
            bf16x8 bfr = *(const bf16x8*)(&Ws[(ct*16+m)*136 + kc*32 + qd*8]);
            acc[ct] = __builtin_amdgcn_mfma_f32_16x16x32_bf16(af, bfr, acc[ct], 0, 0, 0);
        }
    }
    int row = t0 + wv*16 + qd*4;
    #pragma unroll
    for (int ct=0;ct<4;ct++){
        int d = dh*64 + ct*16 + m;
        float bias = bfc[d];
        #pragma unroll
        for (int r=0;r<4;r++)
            Yf[(size_t)(row + r)*C_DIM + d] = acc[ct][r] + bias;
    }
}

// K2: symmetric Gram, 128x64 tiles, XOR-swizzled LDS. (proven R7)
__global__ __launch_bounds__(256) void k_gram(const ushort_t* __restrict__ Xf,
                                              const float* __restrict__ sq,
                                              u64* __restrict__ Hb){
    __shared__ ushort_t Al[128*128];   // 32 KB, swizzled
    __shared__ ushort_t Bl[64*128];    // 16 KB, swizzled
    __shared__ u64 rowW[128];
    __shared__ u64 part[256];
    int tid = threadIdx.x;
    int L = blockIdx.x, b = blockIdx.y;
    int bi = (int)((65.0f - sqrtf(4225.0f - 4.0f*(float)L)) * 0.5f);
    while (bi > 0 && bi*(65-bi) > L) --bi;
    while ((bi+1)*(65-(bi+1)) <= L) ++bi;
    int bj = L - bi*(65-bi) + 2*bi;
    int i0 = bi*128, j0 = bj*64;
    const ushort_t* XfA = Xf + (size_t)(b*N_TOK + i0)*C_DIM;
    const ushort_t* XfB = Xf + (size_t)(b*N_TOK + j0)*C_DIM;
    #pragma unroll
    for (int k=0;k<8;k++){
        int q = tid + 256*k;            // 2048 x 16B : 128 rows
        int row = q >> 4, c16 = q & 15;
        int off = row*256 + ((c16*16) ^ ((row & 7) << 4));
        *(uint4*)((char*)Al + off) = *(const uint4*)(XfA + row*C_DIM + c16*8);
    }
    #pragma unroll
    for (int k=0;k<4;k++){
        int q = tid + 256*k;            // 1024 x 16B : 64 rows
        int row = q >> 4, c16 = q & 15;
        int off = row*256 + ((c16*16) ^ ((row & 7) << 4));
        *(uint4*)((char*)Bl + off) = *(const uint4*)(XfB + row*C_DIM + c16*8);
    }
    __syncthreads();
    int wv = tid >> 6, lane = tid & 63;
    int qd = lane >> 4, m = lane & 15;
    f32x4 acc[2][4] = {{{0,0,0,0},{0,0,0,0},{0,0,0,0},{0,0,0,0}},
                       {{0,0,0,0},{0,0,0,0},{0,0,0,0},{0,0,0,0}}};
    #pragma unroll
    for (int kc=0;kc<4;kc++){
        int coff = (kc*64 + qd*16) ^ ((m & 7) << 4);
        bf16x8 a0 = *(const bf16x8*)((char*)Al + (wv*32 +      m)*256 + coff);
        bf16x8 a1 = *(const bf16x8*)((char*)Al + (wv*32 + 16 + m)*256 + coff);
        #pragma unroll
        for (int ct=0;ct<4;ct++){
            bf16x8 bfr = *(const bf16x8*)((char*)Bl + (ct*16 + m)*256 + coff);
            acc[0][ct] = __builtin_amdgcn_mfma_f32_16x16x32_bf16(a0, bfr, acc[0][ct], 0, 0, 0);
            acc[1][ct] = __builtin_amdgcn_mfma_f32_16x16x32_bf16(a1, bfr, acc[1][ct], 0, 0, 0);
        }
    }
    float sqj[4];
    #pragma unroll
    for (int ct=0;ct<4;ct++) sqj[ct] = sq[b*N_TOK + j0 + ct*16 + m];
    #pragma unroll
    for (int rt=0;rt<2;rt++){
        int lr = wv*32 + rt*16 + qd*4;
        int ib = i0 + lr;
        float sqi[4];
        #pragma unroll
        for (int r=0;r<4;r++) sqi[r] = sq[b*N_TOK + ib + r];
        #pragma unroll
        for (int r=0;r<4;r++){
            u64 bits = 0;
            #pragma unroll
            for (int ct=0;ct<4;ct++){
                float d2 = sqi[r] + sqj[ct] - 2.0f*acc[rt][ct][r];
                if (d2 < THRESH2) bits |= (u64)1 << (ct*16 + m);
            }
            bits |= shfl_xor_u64(bits, 1);
            bits |= shfl_xor_u64(bits, 2);
            bits |= shfl_xor_u64(bits, 4);
            bits |= shfl_xor_u64(bits, 8);
            if (m == 0){
                Hb[(size_t)(b*N_TOK + ib + r)*64 + bj] = bits;
                rowW[lr + r] = bits;
            }
        }
    }
    __syncthreads();
    {
        int jj = tid & 63, hw = (tid>>6)&1, sub = tid>>7;
        u64 p = 0;
        int ibase = hw*64 + sub*32;
        #pragma unroll 8
        for (int ii=0; ii<32; ii++){
            u64 wrd = rowW[ibase + ii];
            p |= ((wrd >> jj) & 1ull) << (sub*32 + ii);
        }
        part[tid] = p;
    }
    __syncthreads();
    if (tid < 128){
        int jj = tid & 63, hw = tid >> 6;
        u64 wt = part[tid] | part[tid + 128];
        Hb[(size_t)(b*N_TOK + j0 + jj)*64 + 2*bi + hw] = wt;
    }
}

// K3: TWO-HOP aggregation in ONE pass (proven numerics; 512 blocks,
// 4 rows per wave, register-accumulated BN partials).
__global__ __launch_bounds__(256) void k_agg2(const u64* __restrict__ Hb,
                                              const float* __restrict__ Yf,
                                              float* __restrict__ Xe,
                                              float* __restrict__ bnp){
    __shared__ float r1[4][128];
    __shared__ float r2[4][128];
    int tid = threadIdx.x;
    int wv = tid >> 6, lane = tid & 63;
    float s1a=0.f, s1b=0.f, s2a=0.f, s2b=0.f;
    #pragma unroll
    for (int k=0;k<4;k++){
        int row = blockIdx.x*16 + wv + 4*k;     // [0, 8192)
        int b = row >> 12;
        const float* Vb = Yf + (size_t)b*N_TOK*C_DIM;
        u64 myw = Hb[(size_t)row*64 + lane];
        int ci = wave_popc_reduce(myw);
        float nrm_i = (ci > 0) ? 1.0f/(float)ci : 0.0f;
        float acc0 = 0.f, acc1 = 0.f;
        u64 nz = __ballot(myw != 0);
        while (nz){
            int wdi = __builtin_ctzll(nz);
            nz &= nz - 1;
            u64 mw = shfl_u64(myw, wdi);
            while (mw){
                int j = wdi*64 + __builtin_ctzll(mw);   // local token in batch
                mw &= mw - 1;
                int jrow = (b << 12) + j;
                u64 jw; float nrm_j;
                if (jrow == row){ jw = myw; nrm_j = nrm_i; }
                else {
                    jw = Hb[(size_t)jrow*64 + lane];
                    int jc = wave_popc_reduce(jw);
                    nrm_j = (jc > 0) ? 1.0f/(float)jc : 0.0f;
                }
                float sub0 = 0.f, sub1 = 0.f;
                u64 jnz = __ballot(jw != 0);
                while (jnz){
                    int w2 = __builtin_ctzll(jnz);
                    jnz &= jnz - 1;
                    u64 m2 = shfl_u64(jw, w2);
                    while (m2){
                        int kk = w2*64 + __builtin_ctzll(m2);
                        m2 &= m2 - 1;
                        sub0 += Vb[(size_t)kk*C_DIM + lane];
                        sub1 += Vb[(size_t)kk*C_DIM + lane + 64];
                    }
                }
                acc0 += nrm_j * sub0;
                acc1 += nrm_j * sub1;
            }
        }
        size_t o = (size_t)row*C_DIM;
        float xe0 = Yf[o + lane]      + nrm_i*acc0;
        float xe1 = Yf[o + lane + 64] + nrm_i*acc1;
        Xe[o + lane]      = xe0;
        Xe[o + lane + 64] = xe1;
        s1a += xe0; s2a += xe0*xe0;
        s1b += xe1; s2b += xe1*xe1;
    }
    r1[wv][lane]      = s1a;
    r1[wv][lane + 64] = s1b;
    r2[wv][lane]      = s2a;
    r2[wv][lane + 64] = s2b;
    __syncthreads();
    if (tid < 128){
        float s1 = r1[0][tid]+r1[1][tid]+r1[2][tid]+r1[3][tid];
        float s2 = r2[0][tid]+r2[1][tid]+r2[2][tid]+r2[3][tid];
        int prt = blockIdx.x & 7;
        atomicAdd(&bnp[prt*256 + tid],       s1);
        atomicAdd(&bnp[prt*256 + 128 + tid], s2);
    }
}

// K4: BN affine + SiLU + transpose back to [B,C,N]. 256 blocks, 4 n-subtiles each.
__global__ void k_out(const float* __restrict__ Xe,
                      const float* __restrict__ bnp,
                      const float* __restrict__ gamma,
                      const float* __restrict__ beta,
                      float* __restrict__ out){
    __shared__ float tile[32][33];
    int tx = threadIdx.x, ty = threadIdx.y;
    int c0 = blockIdx.y*32, b = blockIdx.z;
    int c = c0 + tx;
    float s1 = 0.f, s2 = 0.f;
    #pragma unroll
    for (int p=0;p<8;p++){
        s1 += bnp[p*256 + c];
        s2 += bnp[p*256 + 128 + c];
    }
    float inv = 1.0f / (float)NTOT;
    float mean = s1 * inv;
    float var  = s2*inv - mean*mean;
    float scale = gamma[c] * rsqrtf(var + 1e-5f);
    float shift = beta[c] - mean*scale;
    #pragma unroll
    for (int sub=0; sub<4; ++sub){
        int n0 = (blockIdx.x*4 + sub)*32;
        #pragma unroll
        for (int k=0;k<4;k++){
            int nl = ty + 8*k;
            float v = Xe[(size_t)(b*N_TOK + n0 + nl)*C_DIM + c];
            v = scale*v + shift;
            float sg = 1.0f/(1.0f + __expf(-v));
            tile[tx][nl] = v * sg;
        }
        __syncthreads();
        #pragma unroll
        for (int k=0;k<4;k++){
            int cl = ty + 8*k;
            out[(size_t)(b*C_DIM + c0 + cl)*N_TOK + n0 + tx] = tile[cl][tx];
        }
        __syncthreads();
    }
}

extern "C" void kernel_launch(void* const* d_in, const int* in_sizes, int n_in,
                              void* d_out, int out_size, void* d_ws, size_t ws_size,
                              hipStream_t stream){
    if (ws_size < WS_NEED) return;
    const float* x     = (const float*)d_in[0];
    const float* W     = (const float*)d_in[1];
    const float* bfc   = (const float*)d_in[2];
    const float* gamma = (const float*)d_in[3];
    const float* beta  = (const float*)d_in[4];
    char* ws = (char*)d_ws;
    ushort_t* Xf = (ushort_t*)(ws + XF_OFF);
    float*    Yf = (float*)(ws + YF_OFF);
    float*    Xe = (float*)(ws + XE_OFF);
    float*    sqp= (float*)(ws + SQ_OFF);
    float*    bnp= (float*)(ws + BN_OFF);
    u64*      Hb = (u64*)(ws + HB_OFF);
    float*    outp = (float*)d_out;

    k_fc  <<<dim3(128,2),  dim3(256),  0, stream>>>(x, W, bfc, Xf, Yf, sqp, bnp);
    k_gram<<<dim3(1056,2), dim3(256),  0, stream>>>(Xf, sqp, Hb);
    k_agg2<<<dim3(512),    dim3(256),  0, stream>>>(Hb, Yf, Xe, bnp);
    k_out <<<dim3(32,4,2), dim3(32,8), 0, stream>>>(Xe, bnp, gamma, beta, outp);
}